// Round 3
// baseline (200.694 us; speedup 1.0000x reference)
//
#include <hip/hip_runtime.h>

#define HW (512 * 512)
#define GD 200
#define NS 9
#define NF 8
#define NPB 128             // rays per block (2 per lane)
#define BT (64 * NS)        // 576 threads = 9 waves; wave = sample, lane = ray pair

__device__ __forceinline__ void ray_setup(
    float px, float py, float pz, float ex, float ey, float ez, float off,
    float& cx, float& cy, float& cz, float& dx, float& dy, float& dz)
{
    dx = px - ex; dy = py - ey; dz = pz - ez;
    float inv = 1.0f / sqrtf(dx * dx + dy * dy + dz * dz);
    dx *= inv; dy *= inv; dz *= inv;
    cx = px + off * dx; cy = py + off * dy; cz = pz + off * dz;
}

__device__ __forceinline__ void addr_setup(
    float cx, float cy, float cz,
    int& X0, int& X1, int& Y0, int& Y1, int& Z0, int& Z1,
    float& d0, float& d1, float& d2, bool& valid)
{
    valid = (cx >= 0.0f) && (cx < (float)GD) &&
            (cy >= 0.0f) && (cy < (float)GD) &&
            (cz >= 0.0f) && (cz < (float)GD);
    float p0 = cx + 1.0f, p1 = cy + 1.0f, p2 = cz + 1.0f;
    float f0 = floorf(p0), f1 = floorf(p1), f2 = floorf(p2);
    d0 = p0 - f0; d1 = p1 - f1; d2 = p2 - f2;
    int bx = (int)f0, by = (int)f1, bz = (int)f2;
    // padded index i maps to grid[clamp(i-1,0,199)]; valid => bx in [1,200].
    // Clamp unconditionally so invalid lanes still load in-bounds (result discarded).
    X0 = min(max(bx - 1, 0), GD - 1); X1 = min(max(bx, 0), GD - 1);
    Y0 = min(max(by - 1, 0), GD - 1); Y1 = min(max(by, 0), GD - 1);
    Z0 = min(max(bz - 1, 0), GD - 1); Z1 = min(max(bz, 0), GD - 1);
}

__device__ __forceinline__ void gather8(
    const float4* __restrict__ g4,
    int X0, int X1, int Y0, int Y1, int Z0, int Z1,
    float d0, float d1, float d2, float* acc)
{
    float wz0 = 1.0f - d2, wz1 = d2;
#pragma unroll
    for (int f = 0; f < NF; ++f) acc[f] = 0.0f;
#pragma unroll
    for (int ix = 0; ix < 2; ++ix) {
        int X = ix ? X1 : X0;
        float wx = ix ? d0 : (1.0f - d0);
#pragma unroll
        for (int iy = 0; iy < 2; ++iy) {
            int Y = iy ? Y1 : Y0;
            float wy = iy ? d1 : (1.0f - d1);
            float wxy = wx * wy;
            int rowbase = (X * GD + Y) * GD;
            float4 a0 = g4[(size_t)(rowbase + Z0) * 2 + 0];
            float4 a1 = g4[(size_t)(rowbase + Z0) * 2 + 1];
            float4 b0 = g4[(size_t)(rowbase + Z1) * 2 + 0];
            float4 b1 = g4[(size_t)(rowbase + Z1) * 2 + 1];
            float w0 = wxy * wz0, w1 = wxy * wz1;
            acc[0] += w0 * a0.x + w1 * b0.x;
            acc[1] += w0 * a0.y + w1 * b0.y;
            acc[2] += w0 * a0.z + w1 * b0.z;
            acc[3] += w0 * a0.w + w1 * b0.w;
            acc[4] += w0 * a1.x + w1 * b1.x;
            acc[5] += w0 * a1.y + w1 * b1.y;
            acc[6] += w0 * a1.z + w1 * b1.z;
            acc[7] += w0 * a1.w + w1 * b1.w;
        }
    }
}

__global__ __launch_bounds__(BT, 4) void fusion_gather_kernel(
    const float* __restrict__ vpoints,
    const float* __restrict__ veye,
    const float* __restrict__ grid,
    const float* __restrict__ empty_value,
    float* __restrict__ out_values,   // [72][HW]
    float* __restrict__ out_pn,       // [HW][9][3]
    float* __restrict__ out_dirs)     // [HW][3]
{
    __shared__ float pnbuf[NPB * NS * 3];   // [ray][s][c], 13824 B
    __shared__ float dirbuf[NPB * 3];       // 1536 B

    int tid = threadIdx.x;
    int s = tid >> 6;          // sample index 0..8 (= wave id)
    int i = tid & 63;          // lane
    int n0 = blockIdx.x * NPB;
    int nA = n0 + i;
    int nB = n0 + 64 + i;

    float ex = veye[0], ey = veye[1], ez = veye[2];
    float off = (float)(s - NS / 2);

    float pxA = vpoints[nA * 3 + 0], pyA = vpoints[nA * 3 + 1], pzA = vpoints[nA * 3 + 2];
    float pxB = vpoints[nB * 3 + 0], pyB = vpoints[nB * 3 + 1], pzB = vpoints[nB * 3 + 2];

    float cxA, cyA, czA, dxA, dyA, dzA;
    float cxB, cyB, czB, dxB, dyB, dzB;
    ray_setup(pxA, pyA, pzA, ex, ey, ez, off, cxA, cyA, czA, dxA, dyA, dzA);
    ray_setup(pxB, pyB, pzB, ex, ey, ez, off, cxB, cyB, czB, dxB, dyB, dzB);

    if (s == 4) {
        dirbuf[i * 3 + 0] = dxA; dirbuf[i * 3 + 1] = dyA; dirbuf[i * 3 + 2] = dzA;
        dirbuf[(64 + i) * 3 + 0] = dxB; dirbuf[(64 + i) * 3 + 1] = dyB; dirbuf[(64 + i) * 3 + 2] = dzB;
    }

    // pn staging: stride 27 floats across lanes, gcd(27,32)=1 -> conflict-free
    pnbuf[i * 27 + s * 3 + 0] = cxA - (floorf(cxA) + 0.5f);
    pnbuf[i * 27 + s * 3 + 1] = cyA - (floorf(cyA) + 0.5f);
    pnbuf[i * 27 + s * 3 + 2] = czA - (floorf(czA) + 0.5f);
    pnbuf[(64 + i) * 27 + s * 3 + 0] = cxB - (floorf(cxB) + 0.5f);
    pnbuf[(64 + i) * 27 + s * 3 + 1] = cyB - (floorf(cyB) + 0.5f);
    pnbuf[(64 + i) * 27 + s * 3 + 2] = czB - (floorf(czB) + 0.5f);

    int X0A, X1A, Y0A, Y1A, Z0A, Z1A;
    int X0B, X1B, Y0B, Y1B, Z0B, Z1B;
    float d0A, d1A, d2A, d0B, d1B, d2B;
    bool vA, vB;
    addr_setup(cxA, cyA, czA, X0A, X1A, Y0A, Y1A, Z0A, Z1A, d0A, d1A, d2A, vA);
    addr_setup(cxB, cyB, czB, X0B, X1B, Y0B, Y1B, Z0B, Z1B, d0B, d1B, d2B, vB);

    const float4* g4 = (const float4*)grid;
    float accA[NF], accB[NF];
    gather8(g4, X0A, X1A, Y0A, Y1A, Z0A, Z1A, d0A, d1A, d2A, accA);
    gather8(g4, X0B, X1B, Y0B, Y1B, Z0B, Z1B, d0B, d1B, d2B, accB);

    float ev[NF];
#pragma unroll
    for (int f = 0; f < NF; ++f) ev[f] = empty_value[f];

    // values[(s*8+f)][n] — two coalesced 256 B segments per f
#pragma unroll
    for (int f = 0; f < NF; ++f) {
        __builtin_nontemporal_store(vA ? accA[f] : ev[f],
                                    &out_values[(size_t)(s * NF + f) * HW + nA]);
        __builtin_nontemporal_store(vB ? accB[f] : ev[f],
                                    &out_values[(size_t)(s * NF + f) * HW + nB]);
    }

    __syncthreads();

    // block-coalesced writeout: pn = 128*27 = 3456 floats = 6/thread, dirs = 384 floats
    const size_t pn_base = (size_t)n0 * (NS * 3);
#pragma unroll
    for (int k = 0; k < 6; ++k) {
        int idx = tid + k * BT;
        __builtin_nontemporal_store(pnbuf[idx], &out_pn[pn_base + idx]);
    }
    if (tid < NPB * 3)
        __builtin_nontemporal_store(dirbuf[tid], &out_dirs[(size_t)n0 * 3 + tid]);
}

extern "C" void kernel_launch(void* const* d_in, const int* in_sizes, int n_in,
                              void* d_out, int out_size, void* d_ws, size_t ws_size,
                              hipStream_t stream) {
    const float* vpoints = (const float*)d_in[0];
    const float* veye = (const float*)d_in[1];
    // d_in[2] = depth: unused by the computation (only its shape matters)
    const float* grid = (const float*)d_in[3];
    const float* empty_value = (const float*)d_in[4];

    float* out = (float*)d_out;
    float* out_values = out;                          // 72 * HW
    float* out_pn = out + (size_t)NS * NF * HW;       // HW * 9 * 3
    float* out_dirs = out_pn + (size_t)HW * NS * 3;   // HW * 3

    dim3 block(BT);
    dim3 grid_dim(HW / NPB);
    hipLaunchKernelGGL(fusion_gather_kernel, grid_dim, block, 0, stream,
                       vpoints, veye, grid, empty_value,
                       out_values, out_pn, out_dirs);
}

// Round 4
// 172.236 us; speedup vs baseline: 1.1652x; 1.1652x over previous
//
#include <hip/hip_runtime.h>

#define HW (512 * 512)
#define GD 200
#define NS 9
#define NF 8
#define NPB 64              // rays per block
#define BT (NPB * NS)       // 576 threads = 9 waves; wave = sample, lane = ray

__global__ __launch_bounds__(BT, 5) void fusion_gather_kernel(
    const float* __restrict__ vpoints,
    const float* __restrict__ veye,
    const float* __restrict__ grid,
    const float* __restrict__ empty_value,
    float* __restrict__ out_values,   // [72][HW]
    float* __restrict__ out_pn,       // [HW][9][3]
    float* __restrict__ out_dirs)     // [HW][3]
{
    __shared__ float pnbuf[NPB * NS * 3];   // [ray][s][c], 6912 B
    __shared__ float dirbuf[NPB * 3];       // 768 B

    int tid = threadIdx.x;
    int s = tid >> 6;          // sample index 0..8 (= wave id)
    int i = tid & 63;          // lane = ray
    int n0 = blockIdx.x * NPB;
    int n = n0 + i;

    float px = vpoints[n * 3 + 0];
    float py = vpoints[n * 3 + 1];
    float pz = vpoints[n * 3 + 2];
    float ex = veye[0], ey = veye[1], ez = veye[2];

    float dx = px - ex, dy = py - ey, dz = pz - ez;
    float inv = 1.0f / sqrtf(dx * dx + dy * dy + dz * dz);
    dx *= inv; dy *= inv; dz *= inv;

    if (s == 4) {
        dirbuf[i * 3 + 0] = dx;
        dirbuf[i * 3 + 1] = dy;
        dirbuf[i * 3 + 2] = dz;
    }

    float off = (float)(s - NS / 2);
    float cx = px + off * dx;
    float cy = py + off * dy;
    float cz = pz + off * dz;

    // points_normalized = cv - (floor(cv) + 0.5); stride 27 across lanes, gcd(27,32)=1
    pnbuf[i * 27 + s * 3 + 0] = cx - (floorf(cx) + 0.5f);
    pnbuf[i * 27 + s * 3 + 1] = cy - (floorf(cy) + 0.5f);
    pnbuf[i * 27 + s * 3 + 2] = cz - (floorf(cz) + 0.5f);

    bool valid = (cx >= 0.0f) && (cx < (float)GD) &&
                 (cy >= 0.0f) && (cy < (float)GD) &&
                 (cz >= 0.0f) && (cz < (float)GD);

    // reference: p = pts + 1 into edge-padded grid; padded idx j -> grid[clamp(j-1,0,199)]
    // Clamp unconditionally so invalid lanes still load in-bounds (result discarded at store).
    float p0 = cx + 1.0f, p1 = cy + 1.0f, p2 = cz + 1.0f;
    float f0 = floorf(p0), f1 = floorf(p1), f2 = floorf(p2);
    float d0 = p0 - f0, d1 = p1 - f1, d2 = p2 - f2;
    int bx = (int)f0, by = (int)f1, bz = (int)f2;
    int X0 = min(max(bx - 1, 0), GD - 1), X1 = min(max(bx, 0), GD - 1);
    int Y0 = min(max(by - 1, 0), GD - 1), Y1 = min(max(by, 0), GD - 1);
    int Z0 = min(max(bz - 1, 0), GD - 1), Z1 = min(max(bz, 0), GD - 1);

    const float4* __restrict__ g4 = (const float4*)grid;

    // ---- load phase: issue all 16 independent 16B gathers before any consume ----
    int col[4];
    col[0] = (X0 * GD + Y0) * GD;
    col[1] = (X0 * GD + Y1) * GD;
    col[2] = (X1 * GD + Y0) * GD;
    col[3] = (X1 * GD + Y1) * GD;

    float4 c[16];
#pragma unroll
    for (int q = 0; q < 4; ++q) {
        c[q * 4 + 0] = g4[(size_t)(col[q] + Z0) * 2 + 0];
        c[q * 4 + 1] = g4[(size_t)(col[q] + Z0) * 2 + 1];
        c[q * 4 + 2] = g4[(size_t)(col[q] + Z1) * 2 + 0];
        c[q * 4 + 3] = g4[(size_t)(col[q] + Z1) * 2 + 1];
    }

    // ---- weights (computed while loads are in flight) ----
    float wx0 = 1.0f - d0, wx1 = d0;
    float wy0 = 1.0f - d1, wy1 = d1;
    float wz0 = 1.0f - d2, wz1 = d2;
    float wq[4];
    wq[0] = wx0 * wy0; wq[1] = wx0 * wy1; wq[2] = wx1 * wy0; wq[3] = wx1 * wy1;

    // ---- compute phase ----
    float acc[NF];
#pragma unroll
    for (int f = 0; f < NF; ++f) acc[f] = 0.0f;

#pragma unroll
    for (int q = 0; q < 4; ++q) {
        float w0 = wq[q] * wz0, w1 = wq[q] * wz1;
        acc[0] += w0 * c[q * 4 + 0].x + w1 * c[q * 4 + 2].x;
        acc[1] += w0 * c[q * 4 + 0].y + w1 * c[q * 4 + 2].y;
        acc[2] += w0 * c[q * 4 + 0].z + w1 * c[q * 4 + 2].z;
        acc[3] += w0 * c[q * 4 + 0].w + w1 * c[q * 4 + 2].w;
        acc[4] += w0 * c[q * 4 + 1].x + w1 * c[q * 4 + 3].x;
        acc[5] += w0 * c[q * 4 + 1].y + w1 * c[q * 4 + 3].y;
        acc[6] += w0 * c[q * 4 + 1].z + w1 * c[q * 4 + 3].z;
        acc[7] += w0 * c[q * 4 + 1].w + w1 * c[q * 4 + 3].w;
    }

    float ev[NF];
#pragma unroll
    for (int f = 0; f < NF; ++f) ev[f] = empty_value[f];

    // values[(s*8+f)][n] — each wave has fixed s, consecutive n -> coalesced 256 B stores
#pragma unroll
    for (int f = 0; f < NF; ++f)
        __builtin_nontemporal_store(valid ? acc[f] : ev[f],
                                    &out_values[(size_t)(s * NF + f) * HW + n]);

    __syncthreads();

    // block-coalesced writeout of pn (1728 floats = 3 per thread) and dirs (192 floats)
    const size_t pn_base = (size_t)n0 * (NS * 3);
#pragma unroll
    for (int k = 0; k < 3; ++k) {
        int idx = tid + k * BT;
        __builtin_nontemporal_store(pnbuf[idx], &out_pn[pn_base + idx]);
    }
    if (tid < NPB * 3)
        __builtin_nontemporal_store(dirbuf[tid], &out_dirs[(size_t)n0 * 3 + tid]);
}

extern "C" void kernel_launch(void* const* d_in, const int* in_sizes, int n_in,
                              void* d_out, int out_size, void* d_ws, size_t ws_size,
                              hipStream_t stream) {
    const float* vpoints = (const float*)d_in[0];
    const float* veye = (const float*)d_in[1];
    // d_in[2] = depth: unused by the computation (only its shape matters)
    const float* grid = (const float*)d_in[3];
    const float* empty_value = (const float*)d_in[4];

    float* out = (float*)d_out;
    float* out_values = out;                          // 72 * HW
    float* out_pn = out + (size_t)NS * NF * HW;       // HW * 9 * 3
    float* out_dirs = out_pn + (size_t)HW * NS * 3;   // HW * 3

    dim3 block(BT);
    dim3 grid_dim(HW / NPB);
    hipLaunchKernelGGL(fusion_gather_kernel, grid_dim, block, 0, stream,
                       vpoints, veye, grid, empty_value,
                       out_values, out_pn, out_dirs);
}

// Round 5
// 158.165 us; speedup vs baseline: 1.2689x; 1.0890x over previous
//
#include <hip/hip_runtime.h>

#define HW (512 * 512)
#define GD 200
#define NS 9
#define NF 8
#define NPB 64              // rays per block
#define BT (NPB * NS)       // 576 threads = 9 waves; wave = ~7 rays x all 9 samples

__global__ __launch_bounds__(BT) void fusion_gather_kernel(
    const float* __restrict__ vpoints,
    const float* __restrict__ veye,
    const float* __restrict__ grid,
    const float* __restrict__ empty_value,
    float* __restrict__ out_values,   // [72][HW]
    float* __restrict__ out_pn,       // [HW][9][3]
    float* __restrict__ out_dirs)     // [HW][3]
{
    __shared__ float vp[NPB * 3];            // staged vpoints
    __shared__ float pnbuf[NPB * NS * 3];    // [r][s][c] stride 27
    __shared__ float dirbuf[NPB * 3];
    __shared__ float vbuf[NS * NF * 65];     // [72][65] padded: bank = (row+col)%32

    int tid = threadIdx.x;
    int n0 = blockIdx.x * NPB;

    if (tid < NPB * 3) vp[tid] = vpoints[(size_t)n0 * 3 + tid];
    __syncthreads();

    int r = tid / NS;          // ray 0..63 (~7 per wave)
    int s = tid - r * NS;      // sample 0..8

    float px = vp[r * 3 + 0];
    float py = vp[r * 3 + 1];
    float pz = vp[r * 3 + 2];
    float ex = veye[0], ey = veye[1], ez = veye[2];

    float dx = px - ex, dy = py - ey, dz = pz - ez;
    float inv = 1.0f / sqrtf(dx * dx + dy * dy + dz * dz);
    dx *= inv; dy *= inv; dz *= inv;

    if (s == 0) {
        dirbuf[r * 3 + 0] = dx;
        dirbuf[r * 3 + 1] = dy;
        dirbuf[r * 3 + 2] = dz;
    }

    float off = (float)(s - NS / 2);
    float cx = px + off * dx;
    float cy = py + off * dy;
    float cz = pz + off * dz;

    pnbuf[r * 27 + s * 3 + 0] = cx - (floorf(cx) + 0.5f);
    pnbuf[r * 27 + s * 3 + 1] = cy - (floorf(cy) + 0.5f);
    pnbuf[r * 27 + s * 3 + 2] = cz - (floorf(cz) + 0.5f);

    bool valid = (cx >= 0.0f) && (cx < (float)GD) &&
                 (cy >= 0.0f) && (cy < (float)GD) &&
                 (cz >= 0.0f) && (cz < (float)GD);

    // reference: p = pts + 1 into edge-padded grid; padded idx j -> grid[clamp(j-1,0,199)]
    // Clamp unconditionally; invalid lanes load in-bounds, result replaced at store.
    float p0 = cx + 1.0f, p1 = cy + 1.0f, p2 = cz + 1.0f;
    float f0 = floorf(p0), f1 = floorf(p1), f2 = floorf(p2);
    float d0 = p0 - f0, d1 = p1 - f1, d2 = p2 - f2;
    int bx = (int)f0, by = (int)f1, bz = (int)f2;
    int X0 = min(max(bx - 1, 0), GD - 1), X1 = min(max(bx, 0), GD - 1);
    int Y0 = min(max(by - 1, 0), GD - 1), Y1 = min(max(by, 0), GD - 1);
    int Z0 = min(max(bz - 1, 0), GD - 1), Z1 = min(max(bz, 0), GD - 1);

    const float4* __restrict__ g4 = (const float4*)grid;

    // ---- load phase: all 16 independent 16B gathers issued before any consume ----
    int col[4];
    col[0] = (X0 * GD + Y0) * GD;
    col[1] = (X0 * GD + Y1) * GD;
    col[2] = (X1 * GD + Y0) * GD;
    col[3] = (X1 * GD + Y1) * GD;

    float4 c[16];
#pragma unroll
    for (int q = 0; q < 4; ++q) {
        c[q * 4 + 0] = g4[(size_t)(col[q] + Z0) * 2 + 0];
        c[q * 4 + 1] = g4[(size_t)(col[q] + Z0) * 2 + 1];
        c[q * 4 + 2] = g4[(size_t)(col[q] + Z1) * 2 + 0];
        c[q * 4 + 3] = g4[(size_t)(col[q] + Z1) * 2 + 1];
    }

    float wx0 = 1.0f - d0, wx1 = d0;
    float wy0 = 1.0f - d1, wy1 = d1;
    float wz0 = 1.0f - d2, wz1 = d2;
    float wq[4];
    wq[0] = wx0 * wy0; wq[1] = wx0 * wy1; wq[2] = wx1 * wy0; wq[3] = wx1 * wy1;

    float acc[NF];
#pragma unroll
    for (int f = 0; f < NF; ++f) acc[f] = 0.0f;

#pragma unroll
    for (int q = 0; q < 4; ++q) {
        float w0 = wq[q] * wz0, w1 = wq[q] * wz1;
        acc[0] += w0 * c[q * 4 + 0].x + w1 * c[q * 4 + 2].x;
        acc[1] += w0 * c[q * 4 + 0].y + w1 * c[q * 4 + 2].y;
        acc[2] += w0 * c[q * 4 + 0].z + w1 * c[q * 4 + 2].z;
        acc[3] += w0 * c[q * 4 + 0].w + w1 * c[q * 4 + 2].w;
        acc[4] += w0 * c[q * 4 + 1].x + w1 * c[q * 4 + 3].x;
        acc[5] += w0 * c[q * 4 + 1].y + w1 * c[q * 4 + 3].y;
        acc[6] += w0 * c[q * 4 + 1].z + w1 * c[q * 4 + 3].z;
        acc[7] += w0 * c[q * 4 + 1].w + w1 * c[q * 4 + 3].w;
    }

    float ev[NF];
#pragma unroll
    for (int f = 0; f < NF; ++f) ev[f] = empty_value[f];

    // stage values: vbuf[(s*8+f)*65 + r]; 65 ≡ 1 (mod 32) -> bank = (s*8+f+r)%32, spread
#pragma unroll
    for (int f = 0; f < NF; ++f)
        vbuf[(s * NF + f) * 65 + r] = valid ? acc[f] : ev[f];

    __syncthreads();

    // ---- block-coalesced writeout ----
    // values: 72 rows x 64; per k each wave stores one full row (256 B contiguous)
    {
        int col_ = tid & 63;
        int w = tid >> 6;
#pragma unroll
        for (int k = 0; k < 8; ++k) {
            int row = w + k * NS;
            __builtin_nontemporal_store(vbuf[row * 65 + col_],
                                        &out_values[(size_t)row * HW + n0 + col_]);
        }
    }
    // pn: 1728 floats = 3/thread
    const size_t pn_base = (size_t)n0 * (NS * 3);
#pragma unroll
    for (int k = 0; k < 3; ++k) {
        int idx = tid + k * BT;
        __builtin_nontemporal_store(pnbuf[idx], &out_pn[pn_base + idx]);
    }
    if (tid < NPB * 3)
        __builtin_nontemporal_store(dirbuf[tid], &out_dirs[(size_t)n0 * 3 + tid]);
}

extern "C" void kernel_launch(void* const* d_in, const int* in_sizes, int n_in,
                              void* d_out, int out_size, void* d_ws, size_t ws_size,
                              hipStream_t stream) {
    const float* vpoints = (const float*)d_in[0];
    const float* veye = (const float*)d_in[1];
    // d_in[2] = depth: unused (shape only)
    const float* grid = (const float*)d_in[3];
    const float* empty_value = (const float*)d_in[4];

    float* out = (float*)d_out;
    float* out_values = out;                          // 72 * HW
    float* out_pn = out + (size_t)NS * NF * HW;       // HW * 9 * 3
    float* out_dirs = out_pn + (size_t)HW * NS * 3;   // HW * 3

    dim3 block(BT);
    dim3 grid_dim(HW / NPB);
    hipLaunchKernelGGL(fusion_gather_kernel, grid_dim, block, 0, stream,
                       vpoints, veye, grid, empty_value,
                       out_values, out_pn, out_dirs);
}